// Round 3
// baseline (117431.799 us; speedup 1.0000x reference)
//
#include <hip/hip_runtime.h>
#include <cstddef>

#define T_ 1024
#define B_ 64
#define D_ 256
#define L_ 1024
#define DC_ 256
#define H_ 256
#define A_ 256
#define G3 768  // 3*H

__device__ __forceinline__ float bflo(unsigned int w) { return __uint_as_float(w << 16); }
__device__ __forceinline__ float bfhi(unsigned int w) { return __uint_as_float(w & 0xffff0000u); }
__device__ __forceinline__ unsigned short f2bf(float f) {
  unsigned int x = __float_as_uint(f);
  return (unsigned short)((x + 0x7fffu + ((x >> 16) & 1u)) >> 16);
}
__device__ __forceinline__ float fast_tanh(float xx) {
  float e = __expf(2.0f * xx);
  return 1.0f - 2.0f / (e + 1.0f);
}
__device__ __forceinline__ float sigmoidf_(float xx) {
  return 1.0f / (1.0f + __expf(-xx));
}

__global__ void f2bf_kernel(const float* __restrict__ src,
                            unsigned short* __restrict__ dst, int n) {
  int i = (blockIdx.x * blockDim.x + threadIdx.x) * 4;
  if (i < n) {
    float4 v = *(const float4*)(src + i);
    ushort4 o;
    o.x = f2bf(v.x); o.y = f2bf(v.y); o.z = f2bf(v.z); o.w = f2bf(v.w);
    *(ushort4*)(dst + i) = o;
  }
}

// ctxT[b][a][l] = bf16( sum_d context[b][l][d] * Wc[d][a] )
__global__ void ctx_proj_kernel(const float* __restrict__ context,
                                const float* __restrict__ Wc,
                                unsigned short* __restrict__ ctxT) {
  __shared__ float cs[4352];
  const int bid = blockIdx.x;
  const int b = bid >> 6;
  const int l0 = (bid & 63) << 4;
  const int tid = threadIdx.x;
  for (int idx = tid; idx < 16 * DC_; idx += 256) {
    int r = idx >> 8;
    int d = idx & 255;
    cs[r * DC_ + d] = context[((size_t)b * L_ + (l0 + r)) * DC_ + d];
  }
  __syncthreads();
  const int a = tid;
  float acc[16];
#pragma unroll
  for (int r = 0; r < 16; ++r) acc[r] = 0.0f;
  for (int d = 0; d < DC_; ++d) {
    float w = Wc[d * A_ + a];
#pragma unroll
    for (int r = 0; r < 16; ++r) acc[r] += cs[r * DC_ + d] * w;
  }
  __syncthreads();
#pragma unroll
  for (int r = 0; r < 16; ++r) cs[a * 17 + r] = acc[r];
  __syncthreads();
  for (int idx = tid; idx < 16 * A_; idx += 256) {
    int aa = idx >> 4;
    int r = idx & 15;
    ctxT[((size_t)b * A_ + aa) * L_ + l0 + r] = f2bf(cs[aa * 17 + r]);
  }
}

__global__ __launch_bounds__(1024) void encoder_kernel(
    const float* __restrict__ x, const int* __restrict__ lengths,
    const float* __restrict__ context, const int* __restrict__ ctx_lengths,
    const unsigned short* __restrict__ wx_b, const unsigned short* __restrict__ wh_b,
    const float* __restrict__ v,
    const unsigned short* __restrict__ wih_b, const unsigned short* __restrict__ whh_b,
    const float* __restrict__ b_ih, const float* __restrict__ b_hh,
    const unsigned short* __restrict__ ctxT, float* __restrict__ out) {
  __shared__ float xt_s[D_];
  __shared__ float h_s[H_];
  __shared__ float c_s[DC_];
  __shared__ float2 qv_s[A_];     // (.x = q_t[a], .y = v[a])
  __shared__ float bih_s[G3], bhh_s[G3];
  __shared__ float gi_s[G3], gh_s[G3];
  __shared__ float smem_part[8192];  // 32 KB multipurpose reduce buffer
  __shared__ float pv_s[L_];
  __shared__ float wsum[2];

  float4* part4 = (float4*)smem_part;            // 16 KB region
  float4* part4b = (float4*)(smem_part + 4096);  // 12 KB region

  const int b = blockIdx.x;
  const int tid = threadIdx.x;
  const int len = lengths[b];
  const int clen = ctx_lengths[b];
  const unsigned short* ctxTb = ctxT + (size_t)b * A_ * L_;
  const float* ctxb = context + (size_t)b * L_ * DC_;

  const int p4 = tid >> 8, i256 = tid & 255;   // 4-way split
  const int p16 = tid >> 6, i64 = tid & 63;    // 16-way split
  const int pa = tid >> 7, ls = tid & 127;     // 8-way a-split, l-strip of 8

  if (tid < A_) { qv_s[tid] = make_float2(0.0f, v[tid]); h_s[tid] = 0.0f; }
  if (tid < G3) { bih_s[tid] = b_ih[tid]; bhh_s[tid] = b_hh[tid]; }

  for (int t = 0; t < len; ++t) {
    if (tid < 64) {
      *(float4*)&xt_s[tid * 4] =
          *(const float4*)&x[((size_t)t * B_ + b) * D_ + tid * 4];
    }
    __syncthreads();

    // ---- q[a] = xt@Wx + h@Wh : thread (p16,i64) -> 4 cols, k 16-way split
    {
      const int a0 = i64 * 4, k0 = p16 * 16;
      float4 acc = make_float4(0.f, 0.f, 0.f, 0.f);
#pragma unroll
      for (int k = k0; k < k0 + 16; ++k) {
        float xv = xt_s[k];
        uint2 w = *(const uint2*)(wx_b + (size_t)k * A_ + a0);
        acc.x += xv * bflo(w.x); acc.y += xv * bfhi(w.x);
        acc.z += xv * bflo(w.y); acc.w += xv * bfhi(w.y);
      }
#pragma unroll
      for (int k = k0; k < k0 + 16; ++k) {
        float hv = h_s[k];
        uint2 w = *(const uint2*)(wh_b + (size_t)k * A_ + a0);
        acc.x += hv * bflo(w.x); acc.y += hv * bfhi(w.x);
        acc.z += hv * bflo(w.y); acc.w += hv * bfhi(w.y);
      }
      part4[tid] = acc;
    }
    __syncthreads();
    if (tid < A_) {
      const float* pf = smem_part;
      float q = 0.f;
#pragma unroll
      for (int p = 0; p < 16; ++p) q += pf[p * 256 + tid];
      qv_s[tid].x = q;
    }
    __syncthreads();

    // ---- scores: thread (pa,ls) -> l = 8*ls.., a in [32*pa, 32*pa+32)
    {
      float acc[8];
#pragma unroll
      for (int e = 0; e < 8; ++e) acc[e] = 0.f;
      const int l0 = ls * 8;
      if (l0 < clen) {
        const unsigned short* basep = ctxTb + (size_t)(pa * 32) * L_ + l0;
#pragma unroll 8
        for (int aa = 0; aa < 32; ++aa) {
          uint4 w = *(const uint4*)(basep + (size_t)aa * L_);
          float2 qv = qv_s[pa * 32 + aa];
          const float q = qv.x, vv = qv.y;
          acc[0] += vv * fast_tanh(bflo(w.x) + q);
          acc[1] += vv * fast_tanh(bfhi(w.x) + q);
          acc[2] += vv * fast_tanh(bflo(w.y) + q);
          acc[3] += vv * fast_tanh(bfhi(w.y) + q);
          acc[4] += vv * fast_tanh(bflo(w.z) + q);
          acc[5] += vv * fast_tanh(bfhi(w.z) + q);
          acc[6] += vv * fast_tanh(bflo(w.w) + q);
          acc[7] += vv * fast_tanh(bfhi(w.w) + q);
        }
      }
      float* pp = &smem_part[tid * 8];
      *(float4*)pp = make_float4(acc[0], acc[1], acc[2], acc[3]);
      *(float4*)(pp + 4) = make_float4(acc[4], acc[5], acc[6], acc[7]);
    }
    __syncthreads();
    // ---- finalize: reduce over 8 a-groups, exp (no max shift: |score|<=||v||_1~13), sum
    if (tid < 128) {
      const int l0 = tid * 8;
      float s[8];
#pragma unroll
      for (int e = 0; e < 8; ++e) s[e] = 0.f;
#pragma unroll
      for (int p = 0; p < 8; ++p) {
        const float* pp = &smem_part[(p * 128 + tid) * 8];
        float4 u0 = *(const float4*)pp;
        float4 u1 = *(const float4*)(pp + 4);
        s[0] += u0.x; s[1] += u0.y; s[2] += u0.z; s[3] += u0.w;
        s[4] += u1.x; s[5] += u1.y; s[6] += u1.z; s[7] += u1.w;
      }
      float e0 = (l0     < clen) ? __expf(s[0]) : 0.f;
      float e1 = (l0 + 1 < clen) ? __expf(s[1]) : 0.f;
      float e2 = (l0 + 2 < clen) ? __expf(s[2]) : 0.f;
      float e3 = (l0 + 3 < clen) ? __expf(s[3]) : 0.f;
      float e4 = (l0 + 4 < clen) ? __expf(s[4]) : 0.f;
      float e5 = (l0 + 5 < clen) ? __expf(s[5]) : 0.f;
      float e6 = (l0 + 6 < clen) ? __expf(s[6]) : 0.f;
      float e7 = (l0 + 7 < clen) ? __expf(s[7]) : 0.f;
      *(float4*)&pv_s[l0] = make_float4(e0, e1, e2, e3);
      *(float4*)&pv_s[l0 + 4] = make_float4(e4, e5, e6, e7);
      float sm = e0 + e1 + e2 + e3 + e4 + e5 + e6 + e7;
#pragma unroll
      for (int off = 32; off; off >>= 1) sm += __shfl_xor(sm, off);
      if ((tid & 63) == 0) wsum[tid >> 6] = sm;
    }
    __syncthreads();

    // ---- c[d] partials: thread (p16,i64) -> d=4*i64.., l 16-way split (fp32 context)
    {
      const int d0 = i64 * 4;
      const int l0 = p16 * 64, l1 = min(l0 + 64, clen);
      float4 acc = make_float4(0.f, 0.f, 0.f, 0.f);
      for (int l = l0; l < l1; ++l) {
        float pv = pv_s[l];
        float4 cv = *(const float4*)&ctxb[(size_t)l * DC_ + d0];
        acc.x += pv * cv.x; acc.y += pv * cv.y; acc.z += pv * cv.z; acc.w += pv * cv.w;
      }
      part4[tid] = acc;
    }
    __syncthreads();
    if (tid < DC_) {
      const float inv_sum = 1.0f / (wsum[0] + wsum[1]);
      const float* pf = smem_part;
      float cacc = 0.f;
#pragma unroll
      for (int p = 0; p < 16; ++p) cacc += pf[p * 256 + tid];
      c_s[tid] = cacc * inv_sum;
    }
    __syncthreads();

    // ---- GRU partials: thread (p4, jg=i256<192) -> cols j=4*jg.., k 4-way split
    if (i256 < 192) {
      const int j0 = i256 * 4;
      float4 ai = make_float4(0.f, 0.f, 0.f, 0.f);
      float4 ah = make_float4(0.f, 0.f, 0.f, 0.f);
      if (p4 < 2) {
        const int k0 = p4 * 128;
#pragma unroll 4
        for (int k = k0; k < k0 + 128; ++k) {
          float zk = xt_s[k];
          uint2 w = *(const uint2*)(wih_b + (size_t)k * G3 + j0);
          ai.x += zk * bflo(w.x); ai.y += zk * bfhi(w.x);
          ai.z += zk * bflo(w.y); ai.w += zk * bfhi(w.y);
        }
      } else {
        const int k0 = (p4 - 2) * 128;
#pragma unroll 4
        for (int k = k0; k < k0 + 128; ++k) {
          float zk = c_s[k];
          uint2 w = *(const uint2*)(wih_b + (size_t)(k + 256) * G3 + j0);
          ai.x += zk * bflo(w.x); ai.y += zk * bfhi(w.x);
          ai.z += zk * bflo(w.y); ai.w += zk * bfhi(w.y);
        }
      }
      {
        const int k0 = p4 * 64;
#pragma unroll 4
        for (int k = k0; k < k0 + 64; ++k) {
          float hv = h_s[k];
          uint2 w = *(const uint2*)(whh_b + (size_t)k * G3 + j0);
          ah.x += hv * bflo(w.x); ah.y += hv * bfhi(w.x);
          ah.z += hv * bflo(w.y); ah.w += hv * bfhi(w.y);
        }
      }
      part4[p4 * 256 + i256] = ai;
      part4b[p4 * 192 + i256] = ah;
    }
    __syncthreads();
    if (tid < G3) {
      const float* pf = smem_part;
      const float* pfb = smem_part + 4096;
      float gi = bih_s[tid], gh = bhh_s[tid];
#pragma unroll
      for (int p = 0; p < 4; ++p) {
        gi += pf[p * 1024 + tid];
        gh += pfb[p * 768 + tid];
      }
      gi_s[tid] = gi; gh_s[tid] = gh;
    }
    __syncthreads();
    if (tid < H_) {
      float r = sigmoidf_(gi_s[tid] + gh_s[tid]);
      float u = sigmoidf_(gi_s[256 + tid] + gh_s[256 + tid]);
      float n = fast_tanh(gi_s[512 + tid] + r * gh_s[512 + tid]);
      float hn = u * h_s[tid] + (1.0f - u) * n;
      h_s[tid] = hn;
      out[((size_t)t * B_ + b) * H_ + tid] = hn;
    }
    __syncthreads();
  }
  // zero-fill masked timesteps
  const int tail = (T_ - len) * H_;
  for (int idx = tid; idx < tail; idx += 1024) {
    int tt = len + (idx >> 8);
    out[((size_t)tt * B_ + b) * H_ + (idx & 255)] = 0.0f;
  }
  // h_final
  if (tid < H_) out[(size_t)T_ * B_ * H_ + (size_t)b * H_ + tid] = h_s[tid];
}

extern "C" void kernel_launch(void* const* d_in, const int* in_sizes, int n_in,
                              void* d_out, int out_size, void* d_ws, size_t ws_size,
                              hipStream_t stream) {
  const float* x = (const float*)d_in[0];
  const int* lengths = (const int*)d_in[1];
  const float* context = (const float*)d_in[2];
  const int* ctx_lengths = (const int*)d_in[3];
  const float* Wc = (const float*)d_in[4];
  const float* Wx = (const float*)d_in[5];
  const float* Wh = (const float*)d_in[6];
  const float* v = (const float*)d_in[7];
  const float* W_ih = (const float*)d_in[8];
  const float* W_hh = (const float*)d_in[9];
  const float* b_ih = (const float*)d_in[10];
  const float* b_hh = (const float*)d_in[11];
  float* out = (float*)d_out;

  // ws layout (33.4 MB of the >=64 MB proven available):
  unsigned short* ctxT = (unsigned short*)d_ws;                          // B*A*L bf16 = 32 MB
  unsigned short* wih_b = (unsigned short*)((char*)d_ws + (size_t)33554432);
  unsigned short* whh_b = wih_b + (size_t)(D_ + DC_) * G3;               // 512*768
  unsigned short* wx_b = whh_b + (size_t)H_ * G3;                        // 256*768
  unsigned short* wh_b = wx_b + (size_t)D_ * A_;                         // 256*256

  hipLaunchKernelGGL(f2bf_kernel, dim3((D_ + DC_) * G3 / 4 / 256), dim3(256), 0, stream,
                     W_ih, wih_b, (D_ + DC_) * G3);
  hipLaunchKernelGGL(f2bf_kernel, dim3(H_ * G3 / 4 / 256), dim3(256), 0, stream,
                     W_hh, whh_b, H_ * G3);
  hipLaunchKernelGGL(f2bf_kernel, dim3(D_ * A_ / 4 / 256), dim3(256), 0, stream,
                     Wx, wx_b, D_ * A_);
  hipLaunchKernelGGL(f2bf_kernel, dim3(H_ * A_ / 4 / 256), dim3(256), 0, stream,
                     Wh, wh_b, H_ * A_);
  hipLaunchKernelGGL(ctx_proj_kernel, dim3(B_ * (L_ / 16)), dim3(256), 0, stream,
                     context, Wc, ctxT);
  hipLaunchKernelGGL(encoder_kernel, dim3(B_), dim3(1024), 0, stream,
                     x, lengths, context, ctx_lengths, wx_b, wh_b, v,
                     wih_b, whh_b, b_ih, b_hh, ctxT, out);
}

// Round 4
// 53549.426 us; speedup vs baseline: 2.1930x; 2.1930x over previous
//
#include <hip/hip_runtime.h>
#include <cstddef>

#define T_ 1024
#define B_ 64
#define D_ 256
#define L_ 1024
#define DC_ 256
#define H_ 256
#define A_ 256
#define G3 768
#define LQ 256   // L_/4 per block
#define NBLK 4   // blocks per batch

typedef unsigned int uint2v __attribute__((ext_vector_type(2)));
typedef float float4v __attribute__((ext_vector_type(4)));

__device__ __forceinline__ float bflo(unsigned int w) { return __uint_as_float(w << 16); }
__device__ __forceinline__ float bfhi(unsigned int w) { return __uint_as_float(w & 0xffff0000u); }
__device__ __forceinline__ unsigned short f2bf(float f) {
  unsigned int x = __float_as_uint(f);
  return (unsigned short)((x + 0x7fffu + ((x >> 16) & 1u)) >> 16);
}
__device__ __forceinline__ float fast_tanh(float xx) {
  float e = __expf(2.0f * xx);
  return 1.0f - 2.0f / (e + 1.0f);
}
__device__ __forceinline__ float sigmoidf_(float xx) {
  return 1.0f / (1.0f + __expf(-xx));
}
__device__ __forceinline__ void st_agent_f(float* p, float v) {
  __hip_atomic_store(p, v, __ATOMIC_RELAXED, __HIP_MEMORY_SCOPE_AGENT);
}
__device__ __forceinline__ float ld_agent_f(const float* p) {
  return __hip_atomic_load(p, __ATOMIC_RELAXED, __HIP_MEMORY_SCOPE_AGENT);
}
// 4-block group barrier: monotonic counter, release-add + acquire-spin.
__device__ __forceinline__ void group_sync(unsigned int* ctrb, unsigned int target) {
  __syncthreads();
  if (threadIdx.x == 0) {
    __hip_atomic_fetch_add(ctrb, 1u, __ATOMIC_RELEASE, __HIP_MEMORY_SCOPE_AGENT);
    while (__hip_atomic_load(ctrb, __ATOMIC_ACQUIRE, __HIP_MEMORY_SCOPE_AGENT) < target) {
      __builtin_amdgcn_s_sleep(2);
    }
  }
  __syncthreads();
}

__global__ void f2bf_kernel(const float* __restrict__ src,
                            unsigned short* __restrict__ dst, int n) {
  int i = (blockIdx.x * blockDim.x + threadIdx.x) * 4;
  if (i < n) {
    float4 v = *(const float4*)(src + i);
    ushort4 o;
    o.x = f2bf(v.x); o.y = f2bf(v.y); o.z = f2bf(v.z); o.w = f2bf(v.w);
    *(ushort4*)(dst + i) = o;
  }
}

// Pack W_ih columns per block-slice: dst[kb][r][jg] = W_ih[r][g*256 + kb*64 + jj]
__global__ void pack_wih_kernel(const float* __restrict__ W_ih,
                                unsigned short* __restrict__ dst) {
  int idx = blockIdx.x * 256 + threadIdx.x;  // 4*512*192 = 393216
  int kb = idx / (512 * 192);
  int rem = idx % (512 * 192);
  int r = rem / 192, jg = rem % 192;
  int g = jg >> 6, jj = jg & 63;
  int j = g * 256 + kb * 64 + jj;
  dst[idx] = f2bf(W_ih[(size_t)r * G3 + j]);
}
__global__ void pack_whh_kernel(const float* __restrict__ W_hh,
                                unsigned short* __restrict__ dst) {
  int idx = blockIdx.x * 256 + threadIdx.x;  // 4*256*192 = 196608
  int kb = idx / (256 * 192);
  int rem = idx % (256 * 192);
  int r = rem / 192, jg = rem % 192;
  int g = jg >> 6, jj = jg & 63;
  int j = g * 256 + kb * 64 + jj;
  dst[idx] = f2bf(W_hh[(size_t)r * G3 + j]);
}

// ctxT[b][a][l] = bf16( sum_d context[b][l][d] * Wc[d][a] )
__global__ void ctx_proj_kernel(const float* __restrict__ context,
                                const float* __restrict__ Wc,
                                unsigned short* __restrict__ ctxT) {
  __shared__ float cs[4352];
  const int bid = blockIdx.x;
  const int b = bid >> 6;
  const int l0 = (bid & 63) << 4;
  const int tid = threadIdx.x;
  for (int idx = tid; idx < 16 * DC_; idx += 256) {
    int r = idx >> 8;
    int d = idx & 255;
    cs[r * DC_ + d] = context[((size_t)b * L_ + (l0 + r)) * DC_ + d];
  }
  __syncthreads();
  const int a = tid;
  float acc[16];
#pragma unroll
  for (int r = 0; r < 16; ++r) acc[r] = 0.0f;
  for (int d = 0; d < DC_; ++d) {
    float w = Wc[d * A_ + a];
#pragma unroll
    for (int r = 0; r < 16; ++r) acc[r] += cs[r * DC_ + d] * w;
  }
  __syncthreads();
#pragma unroll
  for (int r = 0; r < 16; ++r) cs[a * 17 + r] = acc[r];
  __syncthreads();
  for (int idx = tid; idx < 16 * A_; idx += 256) {
    int aa = idx >> 4;
    int r = idx & 15;
    ctxT[((size_t)b * A_ + aa) * L_ + l0 + r] = f2bf(cs[aa * 17 + r]);
  }
}

__global__ __launch_bounds__(1024) void encoder_kernel(
    const float* __restrict__ x, const int* __restrict__ lengths,
    const float* __restrict__ context, const int* __restrict__ ctx_lengths,
    const unsigned short* __restrict__ wx_b, const unsigned short* __restrict__ wh_b,
    const float* __restrict__ v,
    const unsigned short* __restrict__ wih_pk, const unsigned short* __restrict__ whh_pk,
    const float* __restrict__ b_ih, const float* __restrict__ b_hh,
    const unsigned short* __restrict__ ctxT, float* __restrict__ out,
    float* __restrict__ cpart, float* __restrict__ hx, unsigned int* __restrict__ ctr) {
  __shared__ __align__(16) float xt_s[D_];
  __shared__ __align__(16) float h_s[H_];
  __shared__ __align__(16) float c_s[DC_];
  __shared__ float2 qv_s[A_];
  __shared__ __align__(16) float part[4096];   // 16 KB multipurpose partials
  __shared__ __align__(16) float phh[3072];    // 12 KB gh partials
  __shared__ float pv_s[LQ];
  __shared__ float gatI[192], gatH[192];
  __shared__ float bsl_i[192], bsl_h[192];
  __shared__ float wsum_l[4];

  const int gb = blockIdx.x;
  const int b = gb >> 2, kb = gb & 3;
  const int tid = threadIdx.x;
  const int len = lengths[b];
  const int clen = ctx_lengths[b];
  const int lbase = kb * LQ;
  const unsigned short* ctxTb = ctxT + (size_t)b * A_ * L_;
  const float* ctxb = context + (size_t)b * L_ * DC_;
  const unsigned short* wihp = wih_pk + (size_t)kb * (512 * 192);
  const unsigned short* whhp = whh_pk + (size_t)kb * (256 * 192);
  float* cpart_grp = cpart + (size_t)b * NBLK * 264;
  float* cpart_my = cpart_grp + kb * 264;
  float* hx_b = hx + (size_t)b * 256;
  unsigned int* ctr_b = ctr + b * 32;

  const int p16 = tid >> 6, i64 = tid & 63;

  if (tid < 256) { h_s[tid] = 0.0f; qv_s[tid] = make_float2(0.0f, v[tid]); }
  if (tid < 192) {
    int g = tid >> 6, jj = tid & 63;
    int j = g * 256 + kb * 64 + jj;
    bsl_i[tid] = b_ih[j]; bsl_h[tid] = b_hh[j];
  }
  __syncthreads();

  for (int t = 0; t < len; ++t) {
    // ---- load xt (nt; zero reuse in L2)
    if (tid < 64) {
      float4v xv = __builtin_nontemporal_load(
          (const float4v*)&x[((size_t)t * B_ + b) * D_ + tid * 4]);
      *(float4v*)&xt_s[tid * 4] = xv;
    }
    __syncthreads();

    // ---- q[a] full, redundant per block (weights L2-hot). (p16,i64): 4 cols, k-strip 16
    {
      const int a0 = i64 * 4, k0 = p16 * 16;
      float4v acc = {0.f, 0.f, 0.f, 0.f};
#pragma unroll
      for (int k = k0; k < k0 + 16; ++k) {
        float xv = xt_s[k];
        uint2v w = *(const uint2v*)(wx_b + (size_t)k * A_ + a0);
        acc.x += xv * bflo(w.x); acc.y += xv * bfhi(w.x);
        acc.z += xv * bflo(w.y); acc.w += xv * bfhi(w.y);
      }
#pragma unroll
      for (int k = k0; k < k0 + 16; ++k) {
        float hv = h_s[k];
        uint2v w = *(const uint2v*)(wh_b + (size_t)k * A_ + a0);
        acc.x += hv * bflo(w.x); acc.y += hv * bfhi(w.x);
        acc.z += hv * bflo(w.y); acc.w += hv * bfhi(w.y);
      }
      *(float4v*)&part[tid * 4] = acc;  // = p16*256 + a0
    }
    __syncthreads();
    if (tid < 256) {
      float q = 0.f;
#pragma unroll
      for (int p = 0; p < 16; ++p) q += part[p * 256 + tid];
      qv_s[tid].x = q;
    }
    __syncthreads();

    // ---- scores on l-slice: (pa=p16, i64): 4 l's, a-strip 16 (nt loads)
    {
      const int ll0 = i64 * 4;
      float4v acc = {0.f, 0.f, 0.f, 0.f};
      if (lbase + ll0 < clen) {
        const unsigned short* basep = ctxTb + (size_t)(p16 * 16) * L_ + lbase + ll0;
#pragma unroll 4
        for (int aa = 0; aa < 16; ++aa) {
          uint2v w = __builtin_nontemporal_load((const uint2v*)(basep + (size_t)aa * L_));
          float2 qv = qv_s[p16 * 16 + aa];
          acc.x += qv.y * fast_tanh(bflo(w.x) + qv.x);
          acc.y += qv.y * fast_tanh(bfhi(w.x) + qv.x);
          acc.z += qv.y * fast_tanh(bflo(w.y) + qv.x);
          acc.w += qv.y * fast_tanh(bfhi(w.y) + qv.x);
        }
      }
      *(float4v*)&part[tid * 4] = acc;
    }
    __syncthreads();
    // ---- finalize: reduce 16 a-groups, exp (no max shift: |score|<=||v||_1), wave sums
    if (tid < 256) {
      float s = 0.f;
#pragma unroll
      for (int p = 0; p < 16; ++p) s += part[p * 256 + tid];
      int lg = lbase + tid;
      float e = (lg < clen) ? __expf(s) : 0.f;
      pv_s[tid] = e;
      float sm = e;
#pragma unroll
      for (int off = 32; off; off >>= 1) sm += __shfl_xor(sm, off);
      if ((tid & 63) == 0) wsum_l[tid >> 6] = sm;
    }
    __syncthreads();

    // ---- c-partials over l-slice: (p16,i64): d=4*i64, l-strip 16 (nt fp32 context)
    {
      const int d0 = i64 * 4;
      const int lmax = min(LQ, max(0, clen - lbase));
      const int l0 = p16 * 16, l1 = min(l0 + 16, lmax);
      float4v acc = {0.f, 0.f, 0.f, 0.f};
      for (int l = l0; l < l1; ++l) {
        float pv = pv_s[l];
        float4v cv = __builtin_nontemporal_load(
            (const float4v*)&ctxb[(size_t)(lbase + l) * DC_ + d0]);
        acc.x += pv * cv.x; acc.y += pv * cv.y; acc.z += pv * cv.z; acc.w += pv * cv.w;
      }
      *(float4v*)&part[tid * 4] = acc;
    }
    __syncthreads();
    if (tid < 256) {
      float cp = 0.f;
#pragma unroll
      for (int p = 0; p < 16; ++p) cp += part[p * 256 + tid];
      st_agent_f(&cpart_my[tid], cp);
    }
    if (tid == 0) {
      st_agent_f(&cpart_my[256], wsum_l[0] + wsum_l[1] + wsum_l[2] + wsum_l[3]);
    }
    group_sync(ctr_b, 8u * t + 4u);
    if (tid < 256) {
      float cc = 0.f, ss = 0.f;
#pragma unroll
      for (int k2 = 0; k2 < 4; ++k2) {
        cc += ld_agent_f(cpart_grp + k2 * 264 + tid);
        ss += ld_agent_f(cpart_grp + k2 * 264 + 256);
      }
      c_s[tid] = cc / ss;
    }
    __syncthreads();

    // ---- GRU gates for own 192-col slice: (pq in [0,16), jg4 in [0,48)): 4 cols
    if (tid < 768) {
      const int pq = tid / 48, jg4 = tid % 48;
      float4v ai = {0.f, 0.f, 0.f, 0.f};
      {
        const int r0 = pq * 32;
#pragma unroll 8
        for (int r = r0; r < r0 + 32; ++r) {
          float zk = (r < 256) ? xt_s[r] : c_s[r - 256];
          uint2v w = *(const uint2v*)(wihp + (size_t)r * 192 + jg4 * 4);
          ai.x += zk * bflo(w.x); ai.y += zk * bfhi(w.x);
          ai.z += zk * bflo(w.y); ai.w += zk * bfhi(w.y);
        }
      }
      float4v ah = {0.f, 0.f, 0.f, 0.f};
      {
        const int r0 = pq * 16;
#pragma unroll 8
        for (int r = r0; r < r0 + 16; ++r) {
          float hv = h_s[r];
          uint2v w = *(const uint2v*)(whhp + (size_t)r * 192 + jg4 * 4);
          ah.x += hv * bflo(w.x); ah.y += hv * bfhi(w.x);
          ah.z += hv * bflo(w.y); ah.w += hv * bfhi(w.y);
        }
      }
      *(float4v*)&part[pq * 192 + jg4 * 4] = ai;
      *(float4v*)&phh[pq * 192 + jg4 * 4] = ah;
    }
    __syncthreads();
    if (tid < 192) {
      float gi = bsl_i[tid], gh = bsl_h[tid];
#pragma unroll
      for (int p = 0; p < 16; ++p) { gi += part[p * 192 + tid]; gh += phh[p * 192 + tid]; }
      gatI[tid] = gi; gatH[tid] = gh;
    }
    __syncthreads();
    if (tid < 64) {
      float r = sigmoidf_(gatI[tid] + gatH[tid]);
      float u = sigmoidf_(gatI[64 + tid] + gatH[64 + tid]);
      float n = fast_tanh(gatI[128 + tid] + r * gatH[128 + tid]);
      float hn = u * h_s[kb * 64 + tid] + (1.0f - u) * n;
      st_agent_f(&hx_b[kb * 64 + tid], hn);
      __builtin_nontemporal_store(hn, &out[((size_t)t * B_ + b) * H_ + kb * 64 + tid]);
    }
    group_sync(ctr_b, 8u * t + 8u);
    if (tid < 256) h_s[tid] = ld_agent_f(&hx_b[tid]);
    __syncthreads();
  }

  // zero-fill masked timesteps: block fills its 64-col slice
  {
    const int n = (T_ - len) * 64;
    for (int idx = tid; idx < n; idx += 1024) {
      int tt = len + (idx >> 6);
      int ii = idx & 63;
      __builtin_nontemporal_store(0.0f, &out[((size_t)tt * B_ + b) * H_ + kb * 64 + ii]);
    }
  }
  // h_final: own slice
  if (tid < 64) {
    out[(size_t)T_ * B_ * H_ + (size_t)b * H_ + kb * 64 + tid] = h_s[kb * 64 + tid];
  }
}

extern "C" void kernel_launch(void* const* d_in, const int* in_sizes, int n_in,
                              void* d_out, int out_size, void* d_ws, size_t ws_size,
                              hipStream_t stream) {
  const float* x = (const float*)d_in[0];
  const int* lengths = (const int*)d_in[1];
  const float* context = (const float*)d_in[2];
  const int* ctx_lengths = (const int*)d_in[3];
  const float* Wc = (const float*)d_in[4];
  const float* Wx = (const float*)d_in[5];
  const float* Wh = (const float*)d_in[6];
  const float* v = (const float*)d_in[7];
  const float* W_ih = (const float*)d_in[8];
  const float* W_hh = (const float*)d_in[9];
  const float* b_ih = (const float*)d_in[10];
  const float* b_hh = (const float*)d_in[11];
  float* out = (float*)d_out;

  char* w = (char*)d_ws;
  unsigned short* ctxT = (unsigned short*)w;                        // 33,554,432 B
  unsigned short* wx_b = (unsigned short*)(w + 33554432);           // 131,072 B
  unsigned short* wh_b = (unsigned short*)(w + 33685504);           // 131,072 B
  unsigned short* wih_pk = (unsigned short*)(w + 33816576);         // 786,432 B
  unsigned short* whh_pk = (unsigned short*)(w + 34603008);         // 393,216 B
  float* cpart = (float*)(w + 34996224);                            // 270,336 B
  float* hx = (float*)(w + 35266560);                               // 65,536 B
  unsigned int* ctr = (unsigned int*)(w + 35332096);                // 8,192 B

  hipMemsetAsync(ctr, 0, 8192, stream);
  hipLaunchKernelGGL(f2bf_kernel, dim3(64), dim3(256), 0, stream, Wx, wx_b, D_ * A_);
  hipLaunchKernelGGL(f2bf_kernel, dim3(64), dim3(256), 0, stream, Wh, wh_b, H_ * A_);
  hipLaunchKernelGGL(pack_wih_kernel, dim3(1536), dim3(256), 0, stream, W_ih, wih_pk);
  hipLaunchKernelGGL(pack_whh_kernel, dim3(768), dim3(256), 0, stream, W_hh, whh_pk);
  hipLaunchKernelGGL(ctx_proj_kernel, dim3(B_ * (L_ / 16)), dim3(256), 0, stream,
                     context, Wc, ctxT);
  hipLaunchKernelGGL(encoder_kernel, dim3(B_ * NBLK), dim3(1024), 0, stream,
                     x, lengths, context, ctx_lengths, wx_b, wh_b, v,
                     wih_pk, whh_pk, b_ih, b_hh, ctxT, out, cpart, hx, ctr);
}